// Round 7
// baseline (214.325 us; speedup 1.0000x reference)
//
#include <hip/hip_runtime.h>
#include <hip/hip_bf16.h>
#include <stdint.h>

// NearestUpsampling (x2) + 3x3 VALID conv == per-parity 2x2 conv on original x
// == implicit GEMM M=16*63*63=63504, N=(4 par)*(128 Cout), K=128c*4taps=512.
// R11 = R10 minus the As XOR-swizzle (which was a bank-math mistake).
//   Analysis: with AS_K=520 (260 dw, 260%32=4), the LINEAR b128 K-loop read
//   is already conflict-free (bases tile 32 banks x8 = b128 minimum); the XOR
//   made it 4-way (8.9M conflict cycles measured). R4's 2.54M came from the
//   stage's b64 writes (16 banks, 2x penalty); fixed here by b128 stage writes
//   at LINEAR addresses: bases (lane+g) mod 8 uniform -> all 32 banks x8 =
//   conflict-free. Keeps R10's two-phase streaming epilogue (WRITE_SIZE
//   155->139.5 MB verified; dump/read are 2-way = free).

#define B_    16
#define CIN   128
#define HIN   64
#define WIN   64
#define COUT  128
#define HO    126
#define WO    126
#define M_TOT (B_ * 63 * 63)   // 63504
#define BM    64
#define KTILES 16
#define AS_K  520              // bf16 row stride: 1040 B (16B-aligned)

typedef __bf16 bf16;
typedef __bf16 bf16x8 __attribute__((ext_vector_type(8)));
typedef float  floatx4 __attribute__((ext_vector_type(4)));

// ---------------------------------------------------------------------------
// Prep: combine 3x3 weights into parity 2x2 weights (bf16).
// Layout: wb[(((kt*4 + par)*128 + o)*32 + k32)], k = kt*32+k32 = c*4 + u*2 + v.
// ---------------------------------------------------------------------------
__global__ void prep_weights(const float* __restrict__ w, bf16* __restrict__ wb) {
    int idx = blockIdx.x * 256 + threadIdx.x;
    if (idx >= 4 * KTILES * COUT * 32) return;   // 262144
    int k32 = idx & 31;
    int o   = (idx >> 5) & 127;
    int par = (idx >> 12) & 3;
    int kt  = idx >> 14;
    int k = kt * 32 + k32;
    int c = k >> 2, u = (k >> 1) & 1, v = k & 1;
    int a = par >> 1, bp = par & 1;
    int dy0, dy1, ndy, dx0, dx1, ndx;
    if (u == 0) { if (a == 0) { dy0 = 0; dy1 = 1; ndy = 2; } else { dy0 = 0; dy1 = 0; ndy = 1; } }
    else        { if (a == 0) { dy0 = 2; dy1 = 2; ndy = 1; } else { dy0 = 1; dy1 = 2; ndy = 2; } }
    if (v == 0) { if (bp == 0) { dx0 = 0; dx1 = 1; ndx = 2; } else { dx0 = 0; dx1 = 0; ndx = 1; } }
    else        { if (bp == 0) { dx0 = 2; dx1 = 2; ndx = 1; } else { dx0 = 1; dx1 = 2; ndx = 2; } }
    const float* wp = w + (o * CIN + c) * 9;
    float s = wp[dy0 * 3 + dx0];
    if (ndx == 2) s += wp[dy0 * 3 + dx1];
    if (ndy == 2) { s += wp[dy1 * 3 + dx0]; if (ndx == 2) s += wp[dy1 * 3 + dx1]; }
    wb[idx] = (bf16)s;
}

// ---------------------------------------------------------------------------
// Main kernel. 512 threads = 8 waves: a = wid>>2 (row parity), oq = wid&3
// (o-quarter). Wave: 32 o x 64 m x both bp via mfma(wf, af) -> D[row=o][col=m].
// ---------------------------------------------------------------------------
__global__ __launch_bounds__(512, 4)
void upconv_gemm(const float* __restrict__ x, const bf16* __restrict__ wb,
                 const float* __restrict__ bias, float* __restrict__ out) {
    __shared__ bf16 As[BM * AS_K];             // 66560 B
    float* Ld = reinterpret_cast<float*>(As);  // epilogue reuse: [o][bp][64] = 65536 B

    const int t    = threadIdx.x;
    const int lane = t & 63;
    const int wid  = t >> 6;
    const int a    = wid >> 2;          // output-row parity
    const int oq   = wid & 3;           // o-quarter
    const int quad = lane >> 4;
    const int l15  = lane & 15;
    const int kq   = quad * 8;

    const int m0 = blockIdx.x * BM;

    // --- stage the ENTIRE A tile (all 512 k), linear b128 writes ---
    // Bank math: base = 4*(lane + g) mod 32 over 64 lanes -> every bank hit
    // exactly 8x (the b128 wave minimum) -> conflict-free, no swizzle.
    {
        const int ml = lane;                // m-row handled by this thread
        const int m_mine = m0 + ml;
        const bool mvalid = (m_mine < M_TOT);
        int b_ = 0, p_ = 0, q_ = 0;
        if (mvalid) { b_ = m_mine / 3969; int rr = m_mine - b_ * 3969; p_ = rr / 63; q_ = rr - p_ * 63; }
        const float* xbase = x + ((b_ * CIN) * HIN + p_) * WIN + q_;

        #pragma unroll
        for (int j = 0; j < 8; ++j) {       // granule j: channels c0, c0+1
            const int c0 = wid * 16 + 2 * j;
            float f0[4] = {0.f, 0.f, 0.f, 0.f}, f1[4] = {0.f, 0.f, 0.f, 0.f};
            if (mvalid) {
                const float* pa = xbase + c0 * (HIN * WIN);
                f0[0] = pa[0]; f0[1] = pa[1]; f0[2] = pa[WIN]; f0[3] = pa[WIN + 1];
                const float* pb = pa + (HIN * WIN);
                f1[0] = pb[0]; f1[1] = pb[1]; f1[2] = pb[WIN]; f1[3] = pb[WIN + 1];
            }
            bf16x8 v;
            v[0] = (bf16)f0[0]; v[1] = (bf16)f0[1]; v[2] = (bf16)f0[2]; v[3] = (bf16)f0[3];
            v[4] = (bf16)f1[0]; v[5] = (bf16)f1[1]; v[6] = (bf16)f1[2]; v[7] = (bf16)f1[3];
            const int g = wid * 8 + j;      // granule index (8 elems = 16 B)
            *(bf16x8*)&As[ml * AS_K + g * 8] = v;   // k = c*4 + tap, LINEAR
        }
    }
    __syncthreads();

    // --- K-loop: no barriers, wf straight from global (L2-resident) ---
    const bf16* wwave = wb + ((a * 2) * COUT + oq * 32 + l15) * 32 + kq;

    floatx4 acc[2][4][2] = {};   // [bp][mt][nt]

    #pragma unroll
    for (int kt = 0; kt < KTILES; ++kt) {
        bf16x8 af[4], wf[2][2];
        #pragma unroll
        for (int i = 0; i < 4; ++i)
            af[i] = *(const bf16x8*)&As[(i * 16 + l15) * AS_K + kt * 32 + kq];  // LINEAR
        #pragma unroll
        for (int bp = 0; bp < 2; ++bp)
            #pragma unroll
            for (int nt = 0; nt < 2; ++nt)
                wf[bp][nt] = *(const bf16x8*)(wwave
                    + (kt * 4 * COUT + bp * COUT + nt * 16) * 32);
        #pragma unroll
        for (int bp = 0; bp < 2; ++bp)
            #pragma unroll
            for (int mt = 0; mt < 4; ++mt)
                #pragma unroll
                for (int nt = 0; nt < 2; ++nt)
                    acc[bp][mt][nt] = __builtin_amdgcn_mfma_f32_16x16x32_bf16(
                        wf[bp][nt], af[mt], acc[bp][mt][nt], 0, 0, 0);
    }

    // ---- two-phase epilogue: phase ap handles output-row parity ap ----
    const int b_base = m0 / 3969;
    const int rr0 = m0 - b_base * 3969;
    const int p0  = rr0 / 63;
    const int q   = lane;    // q coordinate within output row

    #pragma unroll
    for (int ap = 0; ap < 2; ++ap) {
        __syncthreads();   // ap=0: As reads done; ap=1: phase-0 Ld reads done

        if (a == ap) {
            // dump this parity's acc -> Ld[o][bp][ml ^ (quad<<4)]  (2-way, free)
            #pragma unroll
            for (int bp = 0; bp < 2; ++bp)
                #pragma unroll
                for (int mt = 0; mt < 4; ++mt)
                    #pragma unroll
                    for (int nt = 0; nt < 2; ++nt)
                        #pragma unroll
                        for (int ri = 0; ri < 4; ++ri) {
                            const int o   = oq * 32 + nt * 16 + quad * 4 + ri;
                            const int mlx = (mt * 16 + l15) ^ (quad << 4);
                            Ld[(o * 2 + bp) * 64 + mlx] = acc[bp][mt][nt][ri];
                        }
        }
        __syncthreads();

        // streaming store: 256 rows (o, pi) of parity ap; 32 rows per wave.
        // One instruction writes a contiguous 504 B output row.
        for (int i = 0; i < 32; ++i) {
            const int rid = wid * 32 + i;      // wave-uniform scalars below
            const int o   = rid >> 1;
            const int pi  = rid & 1;
            int b = b_base, p = p0 + pi;
            if (p > 62) { b += 1; p = 0; }
            if (b >= B_) continue;
            const int base_m = b * 3969 + p * 63;       // m at (b,p,q=0)
            const float bo = bias[o];
            const int m_lane = base_m + q;
            const bool val = (q < 63) && (m_lane >= m0) && (m_lane < m0 + BM) && (m_lane < M_TOT);
            if (val) {
                const int mloc = m_lane - m0;           // 0..63
                const int xsw  = ((o >> 2) & 3) << 4;   // = writer quad << 4
                const float v0 = Ld[(o * 2 + 0) * 64 + (mloc ^ xsw)];
                const float v1 = Ld[(o * 2 + 1) * 64 + (mloc ^ xsw)];
                const int y = 2 * p + ap;
                float* dst = out + b * (COUT * HO * WO) + o * (HO * WO) + y * WO + 2 * q;
                *(float2*)dst = make_float2(v0 + bo, v1 + bo);
            }
        }
    }
}

extern "C" void kernel_launch(void* const* d_in, const int* in_sizes, int n_in,
                              void* d_out, int out_size, void* d_ws, size_t ws_size,
                              hipStream_t stream) {
    const float* x    = (const float*)d_in[0];
    const float* w    = (const float*)d_in[1];
    const float* bias = (const float*)d_in[2];
    float* out = (float*)d_out;
    bf16* wb = (bf16*)d_ws;   // 512 KB

    prep_weights<<<(4 * KTILES * COUT * 32 + 255) / 256, 256, 0, stream>>>(w, wb);

    dim3 grid((M_TOT + BM - 1) / BM);   // 993 blocks
    upconv_gemm<<<grid, 512, 0, stream>>>(x, wb, bias, out);
}

// Round 8
// 213.580 us; speedup vs baseline: 1.0035x; 1.0035x over previous
//
#include <hip/hip_runtime.h>
#include <hip/hip_bf16.h>
#include <stdint.h>

// NearestUpsampling (x2) + 3x3 VALID conv == per-parity 2x2 conv on original x
// == implicit GEMM M=16*63*63=63504, N=(4 par)*(128 Cout), K=128c*4taps=512.
// R12: 2-phase pipelined K-loop (guide T3-minimum / m97 structure).
//   Falsified so far: occupancy(R5), reg-prefetch(R6: 128-reg wall), weight-L2
//   traffic(R8), write locality(R10: -4%), bank conflicts(R11: nil). Remaining
//   theory: per-kt exposed L2/L3 latency, unfixable in-register under the
//   128-reg cap -> prefetch through LDS with global_load_lds (0 VGPR cost).
//   Per kt: W slice (32KB contiguous) gll'd into double-buffered Ws with an
//   involution source-swizzle j^((j>>3)&7) (conflict-free wf ds_read_b128);
//   A slice (64m x 32k) reg-staged per-kt, x loads issued at iter top (T14).
//   One barrier per kt. LDS 74KB -> still 2 blocks/CU. Epilogue = R10/R11
//   verified streaming store, Ld overlays Ws.

#define B_    16
#define CIN   128
#define HIN   64
#define WIN   64
#define COUT  128
#define HO    126
#define WO    126
#define M_TOT (B_ * 63 * 63)   // 63504
#define BM    64
#define KTILES 16
#define WS_ELEMS 16384          // per W buffer: 4par*128o*32k bf16 = 32 KB
#define AS_STRIDE 40            // Asl row stride in elems (80 B, 16B multiple)
#define AS_ELEMS (64 * AS_STRIDE)

typedef __bf16 bf16;
typedef __bf16 bf16x4 __attribute__((ext_vector_type(4)));
typedef __bf16 bf16x8 __attribute__((ext_vector_type(8)));
typedef float  floatx4 __attribute__((ext_vector_type(4)));

// ---------------------------------------------------------------------------
// Prep: combine 3x3 weights into parity 2x2 weights (bf16).
// Layout: wb[(((kt*4 + par)*128 + o)*32 + k32)], k = kt*32+k32 = c*4 + u*2 + v.
// ---------------------------------------------------------------------------
__global__ void prep_weights(const float* __restrict__ w, bf16* __restrict__ wb) {
    int idx = blockIdx.x * 256 + threadIdx.x;
    if (idx >= 4 * KTILES * COUT * 32) return;   // 262144
    int k32 = idx & 31;
    int o   = (idx >> 5) & 127;
    int par = (idx >> 12) & 3;
    int kt  = idx >> 14;
    int k = kt * 32 + k32;
    int c = k >> 2, u = (k >> 1) & 1, v = k & 1;
    int a = par >> 1, bp = par & 1;
    int dy0, dy1, ndy, dx0, dx1, ndx;
    if (u == 0) { if (a == 0) { dy0 = 0; dy1 = 1; ndy = 2; } else { dy0 = 0; dy1 = 0; ndy = 1; } }
    else        { if (a == 0) { dy0 = 2; dy1 = 2; ndy = 1; } else { dy0 = 1; dy1 = 2; ndy = 2; } }
    if (v == 0) { if (bp == 0) { dx0 = 0; dx1 = 1; ndx = 2; } else { dx0 = 0; dx1 = 0; ndx = 1; } }
    else        { if (bp == 0) { dx0 = 2; dx1 = 2; ndx = 1; } else { dx0 = 1; dx1 = 2; ndx = 2; } }
    const float* wp = w + (o * CIN + c) * 9;
    float s = wp[dy0 * 3 + dx0];
    if (ndx == 2) s += wp[dy0 * 3 + dx1];
    if (ndy == 2) { s += wp[dy1 * 3 + dx0]; if (ndx == 2) s += wp[dy1 * 3 + dx1]; }
    wb[idx] = (bf16)s;
}

// ---------------------------------------------------------------------------
// Main kernel. 512 threads = 8 waves: a = wid>>2 (row parity), oq = wid&3
// (o-quarter). Wave: 32 o x 64 m x both bp via mfma(wf, af) -> D[row=o][col=m].
// ---------------------------------------------------------------------------
__global__ __launch_bounds__(512, 4)
void upconv_gemm(const float* __restrict__ x, const bf16* __restrict__ wb,
                 const float* __restrict__ bias, float* __restrict__ out) {
    __shared__ __align__(16) char smem[2 * WS_ELEMS * 2 + 2 * AS_ELEMS * 2]; // 75776 B
    bf16*  Ws  = (bf16*)smem;                        // [2][16384]
    bf16*  Asl = (bf16*)(smem + 2 * WS_ELEMS * 2);   // [2][2560]
    float* Ld  = (float*)smem;                       // epilogue overlay [128][2][64]

    const int t    = threadIdx.x;
    const int lane = t & 63;
    const int wid  = t >> 6;
    const int a    = wid >> 2;          // output-row parity
    const int oq   = wid & 3;           // o-quarter
    const int quad = lane >> 4;
    const int l15  = lane & 15;
    const int kq   = quad * 8;

    const int m0 = blockIdx.x * BM;

    // per-thread x source: row = lane (m-row), channel = kt*8 + wid
    const int m_mine = m0 + lane;
    const bool mvalid = (m_mine < M_TOT);
    int b_ = 0, p_ = 0, q_ = 0;
    if (mvalid) { b_ = m_mine / 3969; int rr = m_mine - b_ * 3969; p_ = rr / 63; q_ = rr - p_ * 63; }
    const float* xpl = x + ((b_ * CIN + wid) * HIN + p_) * WIN + q_;

    // wf read granule base: go = (a*2+bp)*512 + o*4 + quad, o = oq*32+nt*16+l15
    const int go_base = a * 1024 + oq * 128 + l15 * 4 + quad;

    // ---- prologue: stage kt=0 ----
    {
        #pragma unroll
        for (int i = 0; i < 4; ++i) {
            const int j  = i * 512 + t;              // dest slot (16B granule)
            const int js = j ^ ((j >> 3) & 7);       // involution source swizzle
            __builtin_amdgcn_global_load_lds(
                (const __attribute__((address_space(1))) uint32_t*)(const void*)(wb + js * 8),
                (__attribute__((address_space(3))) uint32_t*)(void*)(Ws + j * 8),
                16, 0, 0);
        }
        float f0 = 0.f, f1 = 0.f, f2 = 0.f, f3 = 0.f;
        if (mvalid) { f0 = xpl[0]; f1 = xpl[1]; f2 = xpl[WIN]; f3 = xpl[WIN + 1]; }
        bf16x4 v; v[0] = (bf16)f0; v[1] = (bf16)f1; v[2] = (bf16)f2; v[3] = (bf16)f3;
        *(bf16x4*)&Asl[lane * AS_STRIDE + wid * 4] = v;
    }
    __syncthreads();

    floatx4 acc[2][4][2] = {};   // [bp][mt][nt]

    #pragma unroll 2
    for (int kt = 0; kt < KTILES; ++kt) {
        const int cur = kt & 1;
        const int nxt = cur ^ 1;

        // ---- issue next-kt prefetches FIRST (latency hides under compute) ----
        float f0 = 0.f, f1 = 0.f, f2 = 0.f, f3 = 0.f;
        if (kt < KTILES - 1) {
            #pragma unroll
            for (int i = 0; i < 4; ++i) {
                const int j  = i * 512 + t;
                const int js = j ^ ((j >> 3) & 7);
                __builtin_amdgcn_global_load_lds(
                    (const __attribute__((address_space(1))) uint32_t*)(const void*)(wb + (kt + 1) * WS_ELEMS + js * 8),
                    (__attribute__((address_space(3))) uint32_t*)(void*)(Ws + nxt * WS_ELEMS + j * 8),
                    16, 0, 0);
            }
            const float* pa = xpl + (kt + 1) * 8 * (HIN * WIN);
            if (mvalid) { f0 = pa[0]; f1 = pa[1]; f2 = pa[WIN]; f3 = pa[WIN + 1]; }
        }

        // ---- compute kt from buffers[cur] ----
        bf16x8 af[4], wf[2][2];
        #pragma unroll
        for (int i = 0; i < 4; ++i)
            af[i] = *(const bf16x8*)&Asl[cur * AS_ELEMS + (i * 16 + l15) * AS_STRIDE + kq];
        #pragma unroll
        for (int bp = 0; bp < 2; ++bp)
            #pragma unroll
            for (int nt = 0; nt < 2; ++nt) {
                const int go = go_base + bp * 512 + nt * 64;
                const int s  = go ^ ((go >> 3) & 7);
                wf[bp][nt] = *(const bf16x8*)&Ws[cur * WS_ELEMS + s * 8];
            }
        #pragma unroll
        for (int bp = 0; bp < 2; ++bp)
            #pragma unroll
            for (int mt = 0; mt < 4; ++mt)
                #pragma unroll
                for (int nt = 0; nt < 2; ++nt)
                    acc[bp][mt][nt] = __builtin_amdgcn_mfma_f32_16x16x32_bf16(
                        wf[bp][nt], af[mt], acc[bp][mt][nt], 0, 0, 0);

        // ---- write next A slice (x loads have had the whole compute to land) ----
        if (kt < KTILES - 1) {
            bf16x4 v; v[0] = (bf16)f0; v[1] = (bf16)f1; v[2] = (bf16)f2; v[3] = (bf16)f3;
            *(bf16x4*)&Asl[nxt * AS_ELEMS + lane * AS_STRIDE + wid * 4] = v;
        }
        __syncthreads();
    }

    // ---- two-phase epilogue (R10/R11 verified): phase ap = output-row parity ----
    const int b_base = m0 / 3969;
    const int rr0 = m0 - b_base * 3969;
    const int p0  = rr0 / 63;
    const int q   = lane;    // q coordinate within output row

    #pragma unroll
    for (int ap = 0; ap < 2; ++ap) {
        __syncthreads();   // ap=0: K-loop LDS reads done (Ld overlays Ws)

        if (a == ap) {
            // dump this parity's acc -> Ld[o][bp][ml ^ (quad<<4)]  (2-way, free)
            #pragma unroll
            for (int bp = 0; bp < 2; ++bp)
                #pragma unroll
                for (int mt = 0; mt < 4; ++mt)
                    #pragma unroll
                    for (int nt = 0; nt < 2; ++nt)
                        #pragma unroll
                        for (int ri = 0; ri < 4; ++ri) {
                            const int o   = oq * 32 + nt * 16 + quad * 4 + ri;
                            const int mlx = (mt * 16 + l15) ^ (quad << 4);
                            Ld[(o * 2 + bp) * 64 + mlx] = acc[bp][mt][nt][ri];
                        }
        }
        __syncthreads();

        // streaming store: 256 rows (o, pi) of parity ap; 32 rows per wave.
        // One instruction writes a contiguous 504 B output row.
        for (int i = 0; i < 32; ++i) {
            const int rid = wid * 32 + i;      // wave-uniform scalars below
            const int o   = rid >> 1;
            const int pi  = rid & 1;
            int b = b_base, p = p0 + pi;
            if (p > 62) { b += 1; p = 0; }
            if (b >= B_) continue;
            const int base_m = b * 3969 + p * 63;       // m at (b,p,q=0)
            const float bo = bias[o];
            const int m_lane = base_m + q;
            const bool val = (q < 63) && (m_lane >= m0) && (m_lane < m0 + BM) && (m_lane < M_TOT);
            if (val) {
                const int mloc = m_lane - m0;           // 0..63
                const int xsw  = ((o >> 2) & 3) << 4;   // = writer quad << 4
                const float v0 = Ld[(o * 2 + 0) * 64 + (mloc ^ xsw)];
                const float v1 = Ld[(o * 2 + 1) * 64 + (mloc ^ xsw)];
                const int y = 2 * p + ap;
                float* dst = out + b * (COUT * HO * WO) + o * (HO * WO) + y * WO + 2 * q;
                *(float2*)dst = make_float2(v0 + bo, v1 + bo);
            }
        }
    }
}

extern "C" void kernel_launch(void* const* d_in, const int* in_sizes, int n_in,
                              void* d_out, int out_size, void* d_ws, size_t ws_size,
                              hipStream_t stream) {
    const float* x    = (const float*)d_in[0];
    const float* w    = (const float*)d_in[1];
    const float* bias = (const float*)d_in[2];
    float* out = (float*)d_out;
    bf16* wb = (bf16*)d_ws;   // 512 KB

    prep_weights<<<(4 * KTILES * COUT * 32 + 255) / 256, 256, 0, stream>>>(w, wb);

    dim3 grid((M_TOT + BM - 1) / BM);   // 993 blocks
    upconv_gemm<<<grid, 512, 0, stream>>>(x, wb, bias, out);
}

// Round 9
// 212.402 us; speedup vs baseline: 1.0091x; 1.0055x over previous
//
#include <hip/hip_runtime.h>
#include <hip/hip_bf16.h>
#include <stdint.h>

// NearestUpsampling (x2) + 3x3 VALID conv == per-parity 2x2 conv on original x
// == implicit GEMM M=16*63*63=63504, N=(4 par)*(128 Cout), K=128c*4taps=512.
// R13: BM 64->63 (one block == one (b,p) input row) + whole-row nontemporal
//   stores. Evidence: every round obeys dur ~= hbm_bytes / ~2.0 TB/s, writes
//   sustain only ~1.4-1.5 TB/s; K-loop structure is irrelevant (R5/R6/R8/R11/
//   R12 all neutral). With BM=64 every 504B output row was written by TWO
//   blocks at different times (partial misaligned bursts, double page opens,
//   partial-sector RMW) and 140MB of writes thrashed the 4MB/XCD L2 (evicting
//   wb + x). Now: b=bid/63, p=bid%63, q=lane (all masks/divisions collapse),
//   each output row written ONCE as a single contiguous 504B nt-store burst
//   (L2-bypass). Staging/K-loop = R11 verbatim (verified conflict-free).

#define B_    16
#define CIN   128
#define HIN   64
#define WIN   64
#define COUT  128
#define HO    126
#define WO    126
#define BM    63
#define KTILES 16
#define AS_K  520              // bf16 row stride: 1040 B (16B-aligned)

typedef __bf16 bf16;
typedef __bf16 bf16x8 __attribute__((ext_vector_type(8)));
typedef float  floatx4 __attribute__((ext_vector_type(4)));
typedef float  floatx2 __attribute__((ext_vector_type(2)));

// ---------------------------------------------------------------------------
// Prep: combine 3x3 weights into parity 2x2 weights (bf16).
// Layout: wb[(((kt*4 + par)*128 + o)*32 + k32)], k = kt*32+k32 = c*4 + u*2 + v.
// ---------------------------------------------------------------------------
__global__ void prep_weights(const float* __restrict__ w, bf16* __restrict__ wb) {
    int idx = blockIdx.x * 256 + threadIdx.x;
    if (idx >= 4 * KTILES * COUT * 32) return;   // 262144
    int k32 = idx & 31;
    int o   = (idx >> 5) & 127;
    int par = (idx >> 12) & 3;
    int kt  = idx >> 14;
    int k = kt * 32 + k32;
    int c = k >> 2, u = (k >> 1) & 1, v = k & 1;
    int a = par >> 1, bp = par & 1;
    int dy0, dy1, ndy, dx0, dx1, ndx;
    if (u == 0) { if (a == 0) { dy0 = 0; dy1 = 1; ndy = 2; } else { dy0 = 0; dy1 = 0; ndy = 1; } }
    else        { if (a == 0) { dy0 = 2; dy1 = 2; ndy = 1; } else { dy0 = 1; dy1 = 2; ndy = 2; } }
    if (v == 0) { if (bp == 0) { dx0 = 0; dx1 = 1; ndx = 2; } else { dx0 = 0; dx1 = 0; ndx = 1; } }
    else        { if (bp == 0) { dx0 = 2; dx1 = 2; ndx = 1; } else { dx0 = 1; dx1 = 2; ndx = 2; } }
    const float* wp = w + (o * CIN + c) * 9;
    float s = wp[dy0 * 3 + dx0];
    if (ndx == 2) s += wp[dy0 * 3 + dx1];
    if (ndy == 2) { s += wp[dy1 * 3 + dx0]; if (ndx == 2) s += wp[dy1 * 3 + dx1]; }
    wb[idx] = (bf16)s;
}

// ---------------------------------------------------------------------------
// Main kernel. 512 threads = 8 waves: a = wid>>2 (row parity), oq = wid&3
// (o-quarter). Wave: 32 o x 63 m x both bp via mfma(wf, af) -> D[row=o][col=m].
// One block == one (b,p) input row: q = lane, y = 2p+a.
// ---------------------------------------------------------------------------
__global__ __launch_bounds__(512, 4)
void upconv_gemm(const float* __restrict__ x, const bf16* __restrict__ wb,
                 const float* __restrict__ bias, float* __restrict__ out) {
    __shared__ bf16 As[64 * AS_K];                       // 66560 B
    floatx2* Ld2 = reinterpret_cast<floatx2*>(As);       // overlay [128][65] f2 = 66560 B

    const int t    = threadIdx.x;
    const int lane = t & 63;
    const int wid  = t >> 6;
    const int a    = wid >> 2;          // output-row parity
    const int oq   = wid & 3;           // o-quarter
    const int quad = lane >> 4;
    const int l15  = lane & 15;
    const int kq   = quad * 8;

    const int bid = blockIdx.x;
    const int b   = bid / 63;           // batch
    const int p   = bid - b * 63;       // input row (0..62)

    // --- stage the A tile (63 m-rows x 512 k), linear b128 writes ---
    // Bank math (R11-verified): bases 4*(lane+g) mod 32 -> all 32 banks x8
    // per b128 wave op = conflict-free minimum.
    {
        const bool mvalid = (lane < 63);
        const float* xbase = x + ((b * CIN) * HIN + p) * WIN + lane;   // q = lane

        #pragma unroll
        for (int j = 0; j < 8; ++j) {       // granule j: channels c0, c0+1
            const int c0 = wid * 16 + 2 * j;
            float f0[4] = {0.f, 0.f, 0.f, 0.f}, f1[4] = {0.f, 0.f, 0.f, 0.f};
            if (mvalid) {
                const float* pa = xbase + c0 * (HIN * WIN);
                f0[0] = pa[0]; f0[1] = pa[1]; f0[2] = pa[WIN]; f0[3] = pa[WIN + 1];
                const float* pb = pa + (HIN * WIN);
                f1[0] = pb[0]; f1[1] = pb[1]; f1[2] = pb[WIN]; f1[3] = pb[WIN + 1];
            }
            bf16x8 v;
            v[0] = (bf16)f0[0]; v[1] = (bf16)f0[1]; v[2] = (bf16)f0[2]; v[3] = (bf16)f0[3];
            v[4] = (bf16)f1[0]; v[5] = (bf16)f1[1]; v[6] = (bf16)f1[2]; v[7] = (bf16)f1[3];
            const int g = wid * 8 + j;      // granule index (8 elems = 16 B)
            *(bf16x8*)&As[lane * AS_K + g * 8] = v;   // k = c*4 + tap, LINEAR
        }
    }
    __syncthreads();

    // --- K-loop (R11 verbatim): no barriers, wf straight from global ---
    const bf16* wwave = wb + ((a * 2) * COUT + oq * 32 + l15) * 32 + kq;

    floatx4 acc[2][4][2] = {};   // [bp][mt][nt]

    #pragma unroll
    for (int kt = 0; kt < KTILES; ++kt) {
        bf16x8 af[4], wf[2][2];
        #pragma unroll
        for (int i = 0; i < 4; ++i)
            af[i] = *(const bf16x8*)&As[(i * 16 + l15) * AS_K + kt * 32 + kq];
        #pragma unroll
        for (int bp = 0; bp < 2; ++bp)
            #pragma unroll
            for (int nt = 0; nt < 2; ++nt)
                wf[bp][nt] = *(const bf16x8*)(wwave
                    + (kt * 4 * COUT + bp * COUT + nt * 16) * 32);
        #pragma unroll
        for (int bp = 0; bp < 2; ++bp)
            #pragma unroll
            for (int mt = 0; mt < 4; ++mt)
                #pragma unroll
                for (int nt = 0; nt < 2; ++nt)
                    acc[bp][mt][nt] = __builtin_amdgcn_mfma_f32_16x16x32_bf16(
                        wf[bp][nt], af[mt], acc[bp][mt][nt], 0, 0, 0);
    }

    // ---- two-phase epilogue: phase ap = output-row parity ----
    // Dump: float2 (both bp) with bias; Ld2 stride 65 (pad) -> conflict-free.
    float bv[2][4];
    #pragma unroll
    for (int nt = 0; nt < 2; ++nt)
        #pragma unroll
        for (int ri = 0; ri < 4; ++ri)
            bv[nt][ri] = bias[oq * 32 + nt * 16 + quad * 4 + ri];

    const int y0 = 2 * p;

    #pragma unroll
    for (int ap = 0; ap < 2; ++ap) {
        __syncthreads();   // ap=0: As K-loop reads done; ap=1: phase-0 reads done

        if (a == ap) {
            #pragma unroll
            for (int mt = 0; mt < 4; ++mt)
                #pragma unroll
                for (int nt = 0; nt < 2; ++nt)
                    #pragma unroll
                    for (int ri = 0; ri < 4; ++ri) {
                        const int o = oq * 32 + nt * 16 + quad * 4 + ri;
                        const int q = mt * 16 + l15;          // 63 unused, in-bounds
                        floatx2 r;
                        r[0] = acc[0][mt][nt][ri] + bv[nt][ri];
                        r[1] = acc[1][mt][nt][ri] + bv[nt][ri];
                        Ld2[o * 65 + q] = r;
                    }
        }
        __syncthreads();

        // streaming store: 128 whole output rows (one per o), 16 per wave.
        // One instruction writes a complete, contiguous 504 B row, nt (L2-bypass).
        #pragma unroll
        for (int i = 0; i < 16; ++i) {
            const int o = wid * 16 + i;
            if (lane < 63) {
                floatx2 v = Ld2[o * 65 + lane];
                float* dst = out + ((b * COUT + o) * HO + (y0 + ap)) * WO + 2 * lane;
                __builtin_nontemporal_store(v, (floatx2*)dst);
            }
        }
    }
}

extern "C" void kernel_launch(void* const* d_in, const int* in_sizes, int n_in,
                              void* d_out, int out_size, void* d_ws, size_t ws_size,
                              hipStream_t stream) {
    const float* x    = (const float*)d_in[0];
    const float* w    = (const float*)d_in[1];
    const float* bias = (const float*)d_in[2];
    float* out = (float*)d_out;
    bf16* wb = (bf16*)d_ws;   // 512 KB

    prep_weights<<<(4 * KTILES * COUT * 32 + 255) / 256, 256, 0, stream>>>(w, wb);

    upconv_gemm<<<dim3(B_ * 63), 512, 0, stream>>>(x, wb, bias, out);   // 1008 blocks
}